// Round 10
// baseline (539.012 us; speedup 1.0000x reference)
//
#include <hip/hip_runtime.h>

#define NN 50000
#define NE 625000
#define IND 512
#define HID 128
#define OUTD 40
#define NL 3
#define NB 196  // ceil(NN/256)

typedef short v8s __attribute__((ext_vector_type(8)));
typedef float v4f __attribute__((ext_vector_type(4)));
typedef const __attribute__((address_space(1))) unsigned int gu32;
typedef __attribute__((address_space(3))) unsigned int lu32;

#define MFMA __builtin_amdgcn_mfma_f32_16x16x32_bf16

__device__ inline ushort f2bf(float x) {
    unsigned u = __float_as_uint(x);
    u += 0x7FFF + ((u >> 16) & 1);  // RNE
    return (ushort)(u >> 16);
}
__device__ inline float bf2f(ushort b) { return __uint_as_float(((unsigned)b) << 16); }

__device__ inline void split8(float4 a, float4 b, v8s& hi, v8s& lo) {
    float v[8] = {a.x, a.y, a.z, a.w, b.x, b.y, b.z, b.w};
    v8s h, l;
#pragma unroll
    for (int i = 0; i < 8; i++) {
        ushort hu = f2bf(v[i]);
        h[i] = (short)hu;
        l[i] = (short)f2bf(v[i] - bf2f(hu));
    }
    hi = h;
    lo = l;
}

// async stage NI*NT*16 bytes from global (linear) into LDS (linear), 16B/lane
template <int NI, int NT>
__device__ inline void stage(const ushort* __restrict__ g, ushort* l, int tid) {
    const int wbase = tid & ~63;
#pragma unroll
    for (int j = 0; j < NI; j++) {
        __builtin_amdgcn_global_load_lds(
            (gu32*)((const char*)g + (size_t)(j * NT + tid) * 16),
            (lu32*)((char*)l + (j * NT + wbase) * 16), 16, 0, 0);
    }
}

// ---------------- CSR build ----------------

__global__ __launch_bounds__(256) void count_kernel(const int* __restrict__ dst,
                                                    int* __restrict__ deg) {
    int e = blockIdx.x * 256 + threadIdx.x;
    if (e < NE) atomicAdd(&deg[dst[e]], 1);
}

// hierarchical scan: (1) per-block exclusive prefix + block sum
__global__ __launch_bounds__(256) void scan1(const int* __restrict__ deg,
                                             int* __restrict__ ex,
                                             int* __restrict__ bsum) {
    __shared__ int s[256];
    int t = threadIdx.x;
    int idx = blockIdx.x * 256 + t;
    int d = idx < NN ? deg[idx] : 0;
    s[t] = d;
    __syncthreads();
#pragma unroll
    for (int off = 1; off < 256; off <<= 1) {
        int v = (t >= off) ? s[t - off] : 0;
        __syncthreads();
        s[t] += v;
        __syncthreads();
    }
    if (idx < NN) ex[idx] = s[t] - d;
    if (t == 255) bsum[blockIdx.x] = s[255];
}

// (2) scan the 196 block sums (single block)
__global__ __launch_bounds__(256) void scan2(const int* __restrict__ bsum,
                                             int* __restrict__ bpre) {
    __shared__ int s[256];
    int t = threadIdx.x;
    int d = t < NB ? bsum[t] : 0;
    s[t] = d;
    __syncthreads();
#pragma unroll
    for (int off = 1; off < 256; off <<= 1) {
        int v = (t >= off) ? s[t - off] : 0;
        __syncthreads();
        s[t] += v;
        __syncthreads();
    }
    if (t < NB) bpre[t] = s[t] - d;
}

// (3) rp/cursor = local prefix + block offset
__global__ __launch_bounds__(256) void scan3(const int* __restrict__ deg,
                                             const int* __restrict__ ex,
                                             const int* __restrict__ bpre,
                                             int* __restrict__ rp,
                                             int* __restrict__ cursor) {
    int idx = blockIdx.x * 256 + threadIdx.x;
    if (idx < NN) {
        int v = ex[idx] + bpre[blockIdx.x];
        rp[idx] = v;
        cursor[idx] = v;
        if (idx == NN - 1) rp[NN] = v + deg[idx];
    }
}

__global__ __launch_bounds__(256) void fill_kernel(const int* __restrict__ src,
                                                   const int* __restrict__ dst,
                                                   const float* __restrict__ ew,
                                                   int* __restrict__ cursor,
                                                   int2* __restrict__ csr) {
    int e = blockIdx.x * 256 + threadIdx.x;
    if (e < NE) {
        int d = dst[e];
        int pos = atomicAdd(&cursor[d], 1);
        csr[pos] = make_int2(src[e], __float_as_int(ew[e]));
    }
}

// ---------------- weight packers: transpose + hi/lo split + baked XOR swizzle ----------------
// emb: P[it=k/64][plane][col][kl^((col&7)<<3)]  (chunk = 16384 ushorts = 32KB)

__global__ __launch_bounds__(256) void conv_emb(const float* __restrict__ W,
                                                ushort* __restrict__ P) {
    int idx = blockIdx.x * 256 + threadIdx.x;  // 512k x 128c
    int k = idx >> 7;
    int c = idx & 127;
    float v = W[(size_t)k * HID + c];
    ushort hb = f2bf(v);
    ushort lb = f2bf(v - bf2f(hb));
    int it = k >> 6, kl = k & 63;
    int pos = it * 16384 + c * 64 + (kl ^ ((c & 7) << 3));
    P[pos] = hb;
    P[pos + 8192] = lb;
}

// mlp: P[l][g][q=c/32][plane][cl][k^((c&7)<<3)]  (chunk = 8192 ushorts = 16KB)
__global__ __launch_bounds__(256) void conv_mlp(const float* __restrict__ W1,
                                                const float* __restrict__ W2,
                                                ushort* __restrict__ P) {
    int idx = blockIdx.x * 256 + threadIdx.x;  // 6 * 128k * 128c
    int lg = idx >> 14;
    int r = idx & 16383;
    int k = r >> 7, c = r & 127;
    int l = lg >> 1, g = lg & 1;
    const float* src = (g ? W2 : W1) + (size_t)l * HID * HID;
    float v = src[(size_t)k * HID + c];
    ushort hb = f2bf(v);
    ushort lb = f2bf(v - bf2f(hb));
    int q = c >> 5, cl = c & 31;
    int pos = lg * 32768 + q * 8192 + cl * 128 + (k ^ ((c & 7) << 3));
    P[pos] = hb;
    P[pos + 4096] = lb;
}

// readout W [128][40] f32 -> padded transposed [48][128] bf16 hi/lo
__global__ __launch_bounds__(256) void conv_ro(const float* __restrict__ W,
                                               ushort* __restrict__ Th,
                                               ushort* __restrict__ Tl) {
    int idx = blockIdx.x * 256 + threadIdx.x;  // 48*128 = 6144
    int c = idx >> 7;
    int kk = idx & 127;
    float v = (c < OUTD) ? W[(size_t)kk * OUTD + c] : 0.f;
    ushort h = f2bf(v);
    Th[idx] = h;
    Tl[idx] = f2bf(v - bf2f(h));
}

// ---------------- Embedding GEMM: [NN,512]@[512,128]+b ----------------
// 512 thr = 8 waves / BM=128. W chunks (32KB) async-staged into 2-deep LDS
// ring with counted vmcnt; X per-lane register loads prefetched 1 chunk ahead.

__global__ __launch_bounds__(512) void emb_mfma(const float* __restrict__ X,
                                                const ushort* __restrict__ Wp,
                                                const float* __restrict__ B,
                                                float* __restrict__ H) {
    __shared__ __align__(16) ushort Wb[2][16384];
    const int tid = threadIdx.x;
    const int wid = tid >> 6, lane = tid & 63;
    const int lane15 = lane & 15, kg = (lane >> 4) * 8;
    const int swc = (lane15 & 7) << 3;
    const int brow = blockIdx.x * 128;
    const int grow = brow + wid * 16 + lane15;
    const float* xr = X + (size_t)(grow < NN ? grow : 0) * IND + kg;

    v4f acc[8];
#pragma unroll
    for (int i = 0; i < 8; i++) acc[i] = (v4f)0.f;

    float4 x0 = *reinterpret_cast<const float4*>(xr);
    float4 x1 = *reinterpret_cast<const float4*>(xr + 4);
    float4 x2 = *reinterpret_cast<const float4*>(xr + 32);
    float4 x3 = *reinterpret_cast<const float4*>(xr + 36);
    stage<4, 512>(Wp, &Wb[0][0], tid);

    for (int it = 0; it < 8; ++it) {
        float4 n0, n1, n2, n3;
        if (it < 7) {
            const float* xn = xr + (it + 1) * 64;
            n0 = *reinterpret_cast<const float4*>(xn);
            n1 = *reinterpret_cast<const float4*>(xn + 4);
            n2 = *reinterpret_cast<const float4*>(xn + 32);
            n3 = *reinterpret_cast<const float4*>(xn + 36);
            stage<4, 512>(Wp + (size_t)(it + 1) * 16384, &Wb[(it + 1) & 1][0], tid);
            asm volatile("s_waitcnt vmcnt(8)" ::: "memory");  // prior X + stage done
        } else {
            asm volatile("s_waitcnt vmcnt(0)" ::: "memory");
        }
        __builtin_amdgcn_s_barrier();  // buf[it&1] staged by all waves
        v8s ah0, al0, ah1, al1;
        split8(x0, x1, ah0, al0);
        split8(x2, x3, ah1, al1);
        const ushort* cb = &Wb[it & 1][0];
        const int s0 = kg ^ swc;
        const int s1 = (32 + kg) ^ swc;
        __builtin_amdgcn_s_setprio(1);
#pragma unroll
        for (int nf = 0; nf < 8; nf++) {
            int rb = (nf * 16 + lane15) * 64;
            v8s bh0 = *reinterpret_cast<const v8s*>(&cb[rb + s0]);
            v8s bl0 = *reinterpret_cast<const v8s*>(&cb[8192 + rb + s0]);
            v8s bh1 = *reinterpret_cast<const v8s*>(&cb[rb + s1]);
            v8s bl1 = *reinterpret_cast<const v8s*>(&cb[8192 + rb + s1]);
            v4f a = acc[nf];
            a = MFMA(ah0, bh0, a, 0, 0, 0);
            a = MFMA(al0, bh0, a, 0, 0, 0);
            a = MFMA(ah0, bl0, a, 0, 0, 0);
            a = MFMA(ah1, bh1, a, 0, 0, 0);
            a = MFMA(al1, bh1, a, 0, 0, 0);
            a = MFMA(ah1, bl1, a, 0, 0, 0);
            acc[nf] = a;
        }
        __builtin_amdgcn_s_setprio(0);
        asm volatile("s_waitcnt lgkmcnt(0)" ::: "memory");  // ds_reads complete
        __builtin_amdgcn_s_barrier();                        // before ring overwrite
        x0 = n0; x1 = n1; x2 = n2; x3 = n3;
    }
#pragma unroll
    for (int nf = 0; nf < 8; nf++) {
        int col = nf * 16 + lane15;
        float bias = B[col];
#pragma unroll
        for (int r = 0; r < 4; r++) {
            int g = brow + wid * 16 + (lane >> 4) * 4 + r;
            if (g < NN) H[(size_t)g * HID + col] = acc[nf][r] + bias;
        }
    }
}

// ---- Fused layer: z = gather(h_in) ; h_out = relu(relu(z@W1+b1)@W2+b2) [+ readout] ----
// 256 thr / BM=64 nodes. Phase 1: CSR gather into swizzled Hh/Hl LDS planes
// (half-wave per node, 8-deep ILP), W-ring prefetch issued before gather.
// Phase 2: the verified 8-chunk W-ring GEMM pipeline (unchanged).
// Ping-pong h buffers across layers (read h_in, write h_out) -- no same-buffer race.

template <int LAST>
__global__ __launch_bounds__(256) void mlp_mfma(const float* __restrict__ Hin,
                                                const int* __restrict__ rp,
                                                const int2* __restrict__ csr,
                                                const ushort* __restrict__ Wlp,
                                                const float* __restrict__ B1,
                                                const float* __restrict__ B2,
                                                const ushort* __restrict__ RWh,
                                                const ushort* __restrict__ RWl,
                                                const float* __restrict__ RB,
                                                float* __restrict__ Hout,
                                                float* __restrict__ OUT) {
    __shared__ __align__(16) ushort Wb[3][8192];
    __shared__ __align__(16) ushort Hh[64 * 128];
    __shared__ __align__(16) ushort Hl[64 * 128];
    const int tid = threadIdx.x;
    const int wid = tid >> 6, lane = tid & 63;
    const int lane15 = lane & 15, kg = (lane >> 4) * 8;
    const int swc = (lane15 & 7) << 3;
    const int brow = blockIdx.x * 64;
    const int rowl = wid * 16 + lane15;
    const int sw = (rowl & 7) << 3;

    // issue first two W chunks before the gather so they hide under it
    stage<4, 256>(Wlp, &Wb[0][0], tid);
    stage<4, 256>(Wlp + 8192, &Wb[1][0], tid);

    // ---- Phase 1: gather z for this block's 64 nodes ----
    const int hw = tid >> 5;            // half-wave 0..7, owns rows hw*8..hw*8+7
    const int c4 = (tid & 31) << 2;     // 4 channels per lane
    const float* hp = Hin + c4;
#pragma unroll
    for (int i = 0; i < 8; i++) {
        const int nl = hw * 8 + i;
        const int g = brow + nl;
        v4f a0 = (v4f)0.f, a1 = (v4f)0.f, a2 = (v4f)0.f, a3 = (v4f)0.f;
        if (g < NN) {
            a0 = *reinterpret_cast<const v4f*>(hp + (size_t)g * HID);  // self (eps=0)
            int k = rp[g];
            const int ke = rp[g + 1];
            for (; k + 7 < ke; k += 8) {
                int2 e0 = csr[k], e1 = csr[k + 1], e2 = csr[k + 2], e3 = csr[k + 3];
                int2 e4 = csr[k + 4], e5 = csr[k + 5], e6 = csr[k + 6], e7 = csr[k + 7];
                const v4f v0 = *reinterpret_cast<const v4f*>(hp + (size_t)e0.x * HID);
                const v4f v1 = *reinterpret_cast<const v4f*>(hp + (size_t)e1.x * HID);
                const v4f v2 = *reinterpret_cast<const v4f*>(hp + (size_t)e2.x * HID);
                const v4f v3 = *reinterpret_cast<const v4f*>(hp + (size_t)e3.x * HID);
                const v4f v4 = *reinterpret_cast<const v4f*>(hp + (size_t)e4.x * HID);
                const v4f v5 = *reinterpret_cast<const v4f*>(hp + (size_t)e5.x * HID);
                const v4f v6 = *reinterpret_cast<const v4f*>(hp + (size_t)e6.x * HID);
                const v4f v7 = *reinterpret_cast<const v4f*>(hp + (size_t)e7.x * HID);
                a0 += __int_as_float(e0.y) * v0;
                a1 += __int_as_float(e1.y) * v1;
                a2 += __int_as_float(e2.y) * v2;
                a3 += __int_as_float(e3.y) * v3;
                a0 += __int_as_float(e4.y) * v4;
                a1 += __int_as_float(e5.y) * v5;
                a2 += __int_as_float(e6.y) * v6;
                a3 += __int_as_float(e7.y) * v7;
            }
            for (; k + 1 < ke; k += 2) {
                int2 e0 = csr[k], e1 = csr[k + 1];
                a0 += __int_as_float(e0.y) * *reinterpret_cast<const v4f*>(hp + (size_t)e0.x * HID);
                a1 += __int_as_float(e1.y) * *reinterpret_cast<const v4f*>(hp + (size_t)e1.x * HID);
            }
            if (k < ke) {
                int2 e = csr[k];
                a0 += __int_as_float(e.y) * *reinterpret_cast<const v4f*>(hp + (size_t)e.x * HID);
            }
        }
        v4f zv = (a0 + a1) + (a2 + a3);
        ushort4 hh, ll;
        {
            ushort h0 = f2bf(zv[0]), h1 = f2bf(zv[1]), h2 = f2bf(zv[2]), h3 = f2bf(zv[3]);
            hh = make_ushort4(h0, h1, h2, h3);
            ll = make_ushort4(f2bf(zv[0] - bf2f(h0)), f2bf(zv[1] - bf2f(h1)),
                              f2bf(zv[2] - bf2f(h2)), f2bf(zv[3] - bf2f(h3)));
        }
        const int idx = nl * 128 + (c4 ^ ((nl & 7) << 3));
        *reinterpret_cast<ushort4*>(&Hh[idx]) = hh;
        *reinterpret_cast<ushort4*>(&Hl[idx]) = ll;
    }
    __syncthreads();  // z planes visible to all waves (also drains W stages)

    // A fragments for GEMM1 from own wave slice
    v8s ah[4], al[4];
#pragma unroll
    for (int ks = 0; ks < 4; ks++) {
        int idx = rowl * 128 + ((ks * 32 + kg) ^ sw);
        ah[ks] = *reinterpret_cast<const v8s*>(&Hh[idx]);
        al[ks] = *reinterpret_cast<const v8s*>(&Hl[idx]);
    }

    v4f acc[8];
#pragma unroll
    for (int i = 0; i < 8; i++) acc[i] = (v4f)0.f;

    // ---- Phase 2: 8-chunk W-ring GEMM pipeline ----
#pragma unroll
    for (int q = 0; q < 8; q++) {
        if (q < 6) {
            stage<4, 256>(Wlp + (size_t)(q + 2) * 8192, &Wb[(q + 2) % 3][0], tid);
            asm volatile("s_waitcnt vmcnt(8)" ::: "memory");
        } else if (q == 6) {
            asm volatile("s_waitcnt vmcnt(4)" ::: "memory");
        } else {
            asm volatile("s_waitcnt vmcnt(0)" ::: "memory");
        }
        __builtin_amdgcn_s_barrier();
        if (q == 4) {  // reload A-frags from hidden (own wave slice)
#pragma unroll
            for (int ks = 0; ks < 4; ks++) {
                int idx = rowl * 128 + ((ks * 32 + kg) ^ sw);
                ah[ks] = *reinterpret_cast<const v8s*>(&Hh[idx]);
                al[ks] = *reinterpret_cast<const v8s*>(&Hl[idx]);
            }
        }
        const ushort* cb = &Wb[q % 3][0];
        const int nfb = (q & 3) * 2;
        __builtin_amdgcn_s_setprio(1);
#pragma unroll
        for (int t = 0; t < 2; t++) {
            int rb = (t * 16 + lane15) * 128;
            v4f a = acc[nfb + t];
#pragma unroll
            for (int ks = 0; ks < 4; ks++) {
                int s = (ks * 32 + kg) ^ swc;
                v8s bh = *reinterpret_cast<const v8s*>(&cb[rb + s]);
                v8s bl = *reinterpret_cast<const v8s*>(&cb[4096 + rb + s]);
                a = MFMA(ah[ks], bh, a, 0, 0, 0);
                a = MFMA(al[ks], bh, a, 0, 0, 0);
                a = MFMA(ah[ks], bl, a, 0, 0, 0);
            }
            acc[nfb + t] = a;
        }
        __builtin_amdgcn_s_setprio(0);
        if (q < 4) {  // GEMM1 chunk done: bias+relu -> hidden LDS slice
#pragma unroll
            for (int t = 0; t < 2; t++) {
                int nf = nfb + t;
                int col = nf * 16 + lane15;
                float b = B1[col];
#pragma unroll
                for (int r = 0; r < 4; r++) {
                    int rl2 = wid * 16 + (lane >> 4) * 4 + r;
                    float v = acc[nf][r] + b;
                    v = v > 0.f ? v : 0.f;
                    ushort hb = f2bf(v);
                    int idx = rl2 * 128 + (col ^ ((rl2 & 7) << 3));
                    Hh[idx] = hb;
                    Hl[idx] = f2bf(v - bf2f(hb));
                }
                acc[nf] = (v4f)0.f;
            }
        } else if (LAST == 0) {
#pragma unroll
            for (int t = 0; t < 2; t++) {
                int nf = nfb + t;
                int col = nf * 16 + lane15;
                float b = B2[col];
#pragma unroll
                for (int r = 0; r < 4; r++) {
                    int g = brow + wid * 16 + (lane >> 4) * 4 + r;
                    if (g < NN) Hout[(size_t)g * HID + col] = fmaxf(acc[nf][r] + b, 0.f);
                }
            }
        } else {  // LAST: h3 -> hidden LDS slice for readout
#pragma unroll
            for (int t = 0; t < 2; t++) {
                int nf = nfb + t;
                int col = nf * 16 + lane15;
                float b = B2[col];
#pragma unroll
                for (int r = 0; r < 4; r++) {
                    int rl2 = wid * 16 + (lane >> 4) * 4 + r;
                    float v = fmaxf(acc[nf][r] + b, 0.f);
                    ushort hb = f2bf(v);
                    int idx = rl2 * 128 + (col ^ ((rl2 & 7) << 3));
                    Hh[idx] = hb;
                    Hl[idx] = f2bf(v - bf2f(hb));
                }
            }
        }
        asm volatile("s_waitcnt lgkmcnt(0)" ::: "memory");
        __builtin_amdgcn_s_barrier();
    }

    if (LAST) {
#pragma unroll
        for (int ks = 0; ks < 4; ks++) {
            int idx = rowl * 128 + ((ks * 32 + kg) ^ sw);
            ah[ks] = *reinterpret_cast<const v8s*>(&Hh[idx]);
            al[ks] = *reinterpret_cast<const v8s*>(&Hl[idx]);
        }
        v4f a3[3];
#pragma unroll
        for (int i = 0; i < 3; i++) a3[i] = (v4f)0.f;
#pragma unroll
        for (int nf = 0; nf < 3; nf++) {
            const ushort* bp = RWh + (size_t)(nf * 16 + lane15) * HID + kg;
            const ushort* bq = RWl + (size_t)(nf * 16 + lane15) * HID + kg;
            v4f a = a3[nf];
#pragma unroll
            for (int ks = 0; ks < 4; ks++) {
                v8s bh = *reinterpret_cast<const v8s*>(bp + ks * 32);
                v8s bl = *reinterpret_cast<const v8s*>(bq + ks * 32);
                a = MFMA(ah[ks], bh, a, 0, 0, 0);
                a = MFMA(al[ks], bh, a, 0, 0, 0);
                a = MFMA(ah[ks], bl, a, 0, 0, 0);
            }
            a3[nf] = a;
        }
#pragma unroll
        for (int nf = 0; nf < 3; nf++) {
            int col = nf * 16 + lane15;
            if (col < OUTD) {
                float b = RB[col];
#pragma unroll
                for (int r = 0; r < 4; r++) {
                    int g = brow + wid * 16 + (lane >> 4) * 4 + r;
                    if (g < NN) OUT[(size_t)g * OUTD + col] = a3[nf][r] + b;
                }
            }
        }
    }
}

// ---------------- launch ----------------

extern "C" void kernel_launch(void* const* d_in, const int* in_sizes, int n_in,
                              void* d_out, int out_size, void* d_ws, size_t ws_size,
                              hipStream_t stream) {
    const float* features = (const float*)d_in[0];
    const int* src = (const int*)d_in[1];
    const int* dst = (const int*)d_in[2];
    const float* ew = (const float*)d_in[3];
    const float* embW = (const float*)d_in[4];
    const float* embB = (const float*)d_in[5];
    const float* W1 = (const float*)d_in[6];
    const float* B1 = (const float*)d_in[7];
    const float* W2 = (const float*)d_in[8];
    const float* B2 = (const float*)d_in[9];
    const float* roW = (const float*)d_in[10];
    const float* roB = (const float*)d_in[11];
    float* out = (float*)d_out;

    float* hA = (float*)d_ws;                         // NN*HID f32 (ping)
    float* hB = hA + (size_t)NN * HID;                // NN*HID f32 (pong)
    int* rp = (int*)(hB + (size_t)NN * HID);          // NN+16
    int2* csr = (int2*)(rp + NN + 16);                // NE int2
    int* cursor = (int*)(csr + NE);                   // NN
    int* deg = cursor + NN;                           // NN
    int* ex = deg + NN;                               // NN
    int* bsum = ex + NN;                              // NB
    int* bpre = bsum + NB + 4;                        // NB
    ushort* Wemb_p = (ushort*)(bpre + NB + 4);        // 8*16384
    ushort* Wmlp_p = Wemb_p + 8 * 16384;              // NL*8*8192
    ushort* roWt_h = Wmlp_p + (size_t)NL * 8 * 8192;  // 48*128
    ushort* roWt_l = roWt_h + 48 * 128;

    conv_emb<<<256, 256, 0, stream>>>(embW, Wemb_p);
    conv_mlp<<<384, 256, 0, stream>>>(W1, W2, Wmlp_p);
    conv_ro<<<24, 256, 0, stream>>>(roW, roWt_h, roWt_l);

    hipMemsetAsync(deg, 0, NN * sizeof(int), stream);
    count_kernel<<<(NE + 255) / 256, 256, 0, stream>>>(dst, deg);
    scan1<<<NB, 256, 0, stream>>>(deg, ex, bsum);
    scan2<<<1, 256, 0, stream>>>(bsum, bpre);
    scan3<<<NB, 256, 0, stream>>>(deg, ex, bpre, rp, cursor);
    fill_kernel<<<(NE + 255) / 256, 256, 0, stream>>>(src, dst, ew, cursor, csr);

    emb_mfma<<<(NN + 127) / 128, 512, 0, stream>>>(features, Wemb_p, embB, hA);

    const int grid = (NN + 63) / 64;
    // layer 0: hA -> hB ; layer 1: hB -> hA ; layer 2: hA -> out (fused readout)
    mlp_mfma<0><<<grid, 256, 0, stream>>>(hA, rp, csr, Wmlp_p, B1, B2,
                                          roWt_h, roWt_l, roB, hB, out);
    mlp_mfma<0><<<grid, 256, 0, stream>>>(hB, rp, csr, Wmlp_p + (size_t)8 * 8192,
                                          B1 + HID, B2 + HID,
                                          roWt_h, roWt_l, roB, hA, out);
    mlp_mfma<1><<<grid, 256, 0, stream>>>(hA, rp, csr, Wmlp_p + (size_t)16 * 8192,
                                          B1 + 2 * HID, B2 + 2 * HID,
                                          roWt_h, roWt_l, roB, hB, out);
}